// Round 1
// 219.334 us; speedup vs baseline: 1.0089x; 1.0089x over previous
//
#include <hip/hip_runtime.h>

// out[m,k] = D*(w-1)*rowsum(t[m]) broadcast over k (K = D = 2048).
//
// R1-R8 (prior session): every FUSED variant lands 71-82 us (~3.8 TB/s
// effective vs 268 MB / 6.3 TB/s = 42 us floor). Root cause: fused shape
// alternates read and write bursts at CU level (read row -> drain -> reduce
// -> write row), so neither stream runs pure; mixed-direction traffic also
// kills DRAM page locality. The reduction (128 MiB -> 64 KB) and broadcast
// (64 KB -> 128 MiB) share zero bytes, so fusion buys nothing.
//
// R9: SPLIT into two pure streams via the 64 KB workspace.
//   Phase 1 (rowsum): pure read. 1 row/wave, all 8 NT dwordx4 issued before
//     any consumption (8 KB in flight/wave x 32 waves/CU = 256 KB/CU).
//     Butterfly-reduce, lane 0 stores scale*sum to ws. Predicted ~21-24 us.
//   Phase 2 (bcast): pure write — same shape as the harness fill kernel,
//     which measurably hits 6.7 TB/s at 9% occupancy. Predicted ~20-22 us.
// Two in-graph launches, same stream (serializes correctly, no sync calls).

#define M_ROWS 16384
#define D_COLS 2048
#define F4_PER_ROW (D_COLS / 4)   // 512
#define WAVES_PER_BLOCK 4
#define BLOCK_SIZE (WAVES_PER_BLOCK * 64)
#define GRID_BLOCKS (M_ROWS / WAVES_PER_BLOCK)   // 4096, 1 row per wave

typedef float vf4 __attribute__((ext_vector_type(4)));

__global__ __launch_bounds__(BLOCK_SIZE)
void rowsum_phase(const float* __restrict__ t,
                  const float* __restrict__ w,
                  float* __restrict__ rs) {
    const int lane = threadIdx.x & 63;
    const int row  = blockIdx.x * WAVES_PER_BLOCK + (threadIdx.x >> 6);

    const vf4* p = reinterpret_cast<const vf4*>(t) + (size_t)row * F4_PER_ROW;

    // Issue all 8 nontemporal loads before any consumption: 8 KB/wave in
    // flight; at 32 resident waves/CU that is 256 KB/CU outstanding.
    vf4 v[8];
    #pragma unroll
    for (int j = 0; j < 8; ++j)
        v[j] = __builtin_nontemporal_load(p + j * 64 + lane);

    float s = 0.0f;
    #pragma unroll
    for (int j = 0; j < 8; ++j)
        s += (v[j].x + v[j].y) + (v[j].z + v[j].w);

    // wave-64 butterfly: lane 0 ends with the full row sum.
    #pragma unroll
    for (int m = 32; m > 0; m >>= 1)
        s += __shfl_xor(s, m, 64);

    if (lane == 0)
        rs[row] = ((float)D_COLS * (w[0] - 1.0f)) * s;
}

__global__ __launch_bounds__(BLOCK_SIZE)
void bcast_phase(const float* __restrict__ rs,
                 float* __restrict__ out) {
    const int lane = threadIdx.x & 63;
    const int row  = blockIdx.x * WAVES_PER_BLOCK + (threadIdx.x >> 6);

    // 64 KB rs table is L2-resident after phase 1; broadcast load is cheap.
    const float val = rs[row];
    vf4 v4;
    v4.x = val; v4.y = val; v4.z = val; v4.w = val;

    vf4* orow = reinterpret_cast<vf4*>(out) + (size_t)row * F4_PER_ROW;
    #pragma unroll
    for (int j = 0; j < 8; ++j)
        __builtin_nontemporal_store(v4, orow + j * 64 + lane);
}

extern "C" void kernel_launch(void* const* d_in, const int* in_sizes, int n_in,
                              void* d_out, int out_size, void* d_ws, size_t ws_size,
                              hipStream_t stream) {
    const float* t = (const float*)d_in[0];
    const float* w = (const float*)d_in[1];
    float* out = (float*)d_out;
    float* rs  = (float*)d_ws;   // 16384 floats = 64 KB scratch

    rowsum_phase<<<GRID_BLOCKS, BLOCK_SIZE, 0, stream>>>(t, w, rs);
    bcast_phase<<<GRID_BLOCKS, BLOCK_SIZE, 0, stream>>>(rs, out);
}